// Round 4
// baseline (423.527 us; speedup 1.0000x reference)
//
#include <hip/hip_runtime.h>
#include <hip/hip_fp16.h>

#define Nn 100000
#define Ee 800000
#define Dd 16
#define Hh 128
#define Oo 3
#define Rr 2
#define HROW 256      // H row: [h_b0(128) | h_b1(128)]
#define Mm (Rr * Nn)
#define CNTB4 ((Ee + 1023) / 1024)                     // 782 place blocks (4 edges/thread)
#define SWB 48
#define INTB ((Nn + 127) / 128)                        // 782 input blocks
#define NT_IN 128
#define FN 32         // nodes per fused-conv block (2 A-subtiles per wave share B-frags)
#define MPAD 516      // LDS M-row stride (halves)
#define OPAD 264      // LDS out-row stride for fused projection

typedef _Float16 half8 __attribute__((ext_vector_type(8)));
typedef _Float16 half4 __attribute__((ext_vector_type(4)));
typedef float floatx4 __attribute__((ext_vector_type(4)));

// ---------------- diagnostic ----------------
__global__ void k_diag(float* out, float v) { out[0] = v; }

// ================= input layer: LDS-free, scalar x loads =================
__global__ __launch_bounds__(256) void k_input(
    const float* __restrict__ mf, const float* __restrict__ ff,
    const float* __restrict__ W1, const float* __restrict__ b1,
    __half* __restrict__ H) {
    int tid = threadIdx.x;
    int n0 = blockIdx.x * NT_IN;
    int j = tid & 127;
    int hf = __builtin_amdgcn_readfirstlane(tid >> 7);
    float wk[Dd];
#pragma unroll
    for (int k = 0; k < Dd; ++k) wk[k] = W1[k * Hh + j];
    float bj = b1[j];
    int nbeg = n0 + hf * 64;
    int nend = nbeg + 64;
    if (nend > Nn) nend = Nn;
#pragma unroll 4
    for (int n = nbeg; n < nend; ++n) {
        const float* xr = mf + (size_t)n * Dd;
        const float* fr = ff + (size_t)n * Dd;
        float a0 = bj, a1 = bj;
#pragma unroll
        for (int k = 0; k < Dd; ++k) {
            float xv = xr[k];
            float fv = fr[k];
            a0 = fmaf(xv, wk[k], a0);          // v_fma: 1 SGPR operand ok
            a1 = fmaf(fv, wk[k], a1);
            a1 = fmaf(-xv, wk[k], a1);         // (fv-xv)*w without 2-SGPR instr
        }
        a0 = a0 > 0.f ? a0 : 0.01f * a0;
        a1 = a1 > 0.f ? a1 : 0.01f * a1;
        H[(size_t)n * HROW + j] = __float2half(a0);
        H[(size_t)n * HROW + Hh + j] = __float2half(a1);
    }
}

// ================= place + swizzle (split from prep for attribution) =================
__global__ __launch_bounds__(256) void k_place(
    const int* __restrict__ ei, const int* __restrict__ et,
    int* __restrict__ cnt, int* __restrict__ eidx, int cap,
    const float* __restrict__ r1root, const float* __restrict__ r1w,
    const float* __restrict__ r2root, const float* __restrict__ r2w,
    __half* __restrict__ Bsw1, __half* __restrict__ Bsw2) {
    int tid = threadIdx.x;
    int sb = blockIdx.x;
    if (sb < CNTB4) {
        // ---- direct placement: FOUR edges per thread, int4 loads coalesced ----
        int e0 = (sb * 256 + tid) * 4;
        if (e0 < Ee) {
            int4 s4 = *(const int4*)(ei + e0);
            int4 d4 = *(const int4*)(ei + Ee + e0);
            int4 t4 = *(const int4*)(et + e0);
            int gb, pos;
            gb = t4.x * Nn + d4.x; pos = atomicAdd(&cnt[gb], 1);
            if (pos < cap) eidx[(size_t)gb * cap + pos] = s4.x;
            gb = t4.y * Nn + d4.y; pos = atomicAdd(&cnt[gb], 1);
            if (pos < cap) eidx[(size_t)gb * cap + pos] = s4.y;
            gb = t4.z * Nn + d4.z; pos = atomicAdd(&cnt[gb], 1);
            if (pos < cap) eidx[(size_t)gb * cap + pos] = s4.z;
            gb = t4.w * Nn + d4.w; pos = atomicAdd(&cnt[gb], 1);
            if (pos < cap) eidx[(size_t)gb * cap + pos] = s4.w;
        }
        return;
    }
    sb -= CNTB4;
    {
        // ---- weight swizzle (verified mapping: tile t holds col (l&15)*8+t) ----
        const float* wroot = (sb < 24) ? r1root : r2root;
        const float* wrel = (sb < 24) ? r1w : r2w;
        __half* Bsw = (sb < 24) ? Bsw1 : Bsw2;
        int idx = (sb % 24) * 256 + tid;
        if (idx >= 8 * 12 * 64) return;
        int l = idx & 63;
        int s = (idx >> 6) % 12;
        int t = (idx >> 6) / 12;
        int n = (l & 15) * 8 + t;
        int k0 = s * 32 + (l >> 4) * 8;
        __half tmp[8];
#pragma unroll
        for (int jj = 0; jj < 8; ++jj) {
            int k = k0 + jj;
            float v = (k < Hh) ? wroot[k * Hh + n] : wrel[(size_t)(k - Hh) * Hh + n];
            tmp[jj] = __float2half(v);
        }
        *(uint4*)(Bsw + (size_t)idx * 8) = *(uint4*)tmp;
    }
}

// ---------------- fused conv: reduction-free gather->LDS + MFMA ----
// FN=32 (this rev): each wave computes TWO 16-node A-subtiles that SHARE every
// B fragment -> Bsw L2 traffic per node halves (was 1.2 GB/dispatch, the dominant
// L2 stream). Phase A: half-wave bucket pairing, hoisted 8-edge broadcasts,
// fp16 pairwise tree (all proven previous rounds).
__global__ __launch_bounds__(256, 4) void k_conv_f(const __half* __restrict__ Hin,
                                                   __half* __restrict__ Hout,
                                                   const int* __restrict__ cnt,
                                                   const int* __restrict__ eidx, int cap,
                                                   const __half* __restrict__ Bsw,
                                                   const float* __restrict__ bias,
                                                   const __half* __restrict__ zrow,
                                                   int do_final,
                                                   const float* __restrict__ Wo,
                                                   const float* __restrict__ bo,
                                                   float* __restrict__ out) {
    __shared__ __align__(16) char smem[FN * MPAD * 2];   // 33024 B; TM, later TO (aliased)
    __shared__ float WoS[Hh * Oo];
    __shared__ float bS[Oo];
    auto TM = (__half(*)[MPAD])smem;
    auto TO = (__half(*)[OPAD])smem;

    int tid = threadIdx.x;
    int n0 = blockIdx.x * FN;
    int wv = tid >> 6;
    int lane = tid & 63;

    if (do_final) {
        for (int i = tid; i < Hh * Oo; i += 256) WoS[i] = Wo[i];
        if (tid < Oo) bS[tid] = bo[tid];
    }

    // ---- Phase A: 64 buckets; wave wv owns node-pairs nl = wv*8 .. wv*8+7 ----
    int hh32 = lane >> 5;      // half-wave id == relation t
    int sl = lane & 31;        // sublane within half-wave
    const __half* zr = zrow + sl * 8;

    // hoisted metadata: 16 cnt loads + 8 edge-list loads, all concurrent
    int cn0[8], cn1[8], sidx[8];
#pragma unroll
    for (int p = 0; p < 8; ++p) {
        int gb0 = n0 + wv * 8 + p;                       // relation-0 bucket
        cn0[p] = cnt[gb0];
        cn1[p] = cnt[gb0 + Nn];
        sidx[p] = eidx[(size_t)(hh32 * Nn + gb0) * cap + sl];
    }

#pragma unroll
    for (int p = 0; p < 8; ++p) {
        int nl = wv * 8 + p;
        int cn_h = hh32 ? cn1[p] : cn0[p];
        int len = cn_h < 32 ? cn_h : 32;
        int mlr = cn0[p] > cn1[p] ? cn0[p] : cn1[p];
        int maxlen = mlr < 32 ? mlr : 32;

        // broadcast first 8 edge ids up-front (one lgkm wait, then loads free-run)
        int bc[8];
#pragma unroll
        for (int u = 0; u < 8; ++u) bc[u] = __shfl(sidx[p], u, 32);

        float2 ac[4];
#pragma unroll
        for (int j = 0; j < 4; ++j) { ac[j].x = 0.f; ac[j].y = 0.f; }

        // round 0: edges 0..3 (always; invalid slots read the hot zero-row)
        {
            half8 v0 = *(const half8*)(const void*)((0 < len) ? Hin + (size_t)bc[0] * HROW + sl * 8 : zr);
            half8 v1 = *(const half8*)(const void*)((1 < len) ? Hin + (size_t)bc[1] * HROW + sl * 8 : zr);
            half8 v2 = *(const half8*)(const void*)((2 < len) ? Hin + (size_t)bc[2] * HROW + sl * 8 : zr);
            half8 v3 = *(const half8*)(const void*)((3 < len) ? Hin + (size_t)bc[3] * HROW + sl * 8 : zr);
            half8 s = (v0 + v1) + (v2 + v3);             // fp16 tree: 2 roundings max
#pragma unroll
            for (int j = 0; j < 4; ++j) {
                ac[j].x += (float)s[2 * j];
                ac[j].y += (float)s[2 * j + 1];
            }
        }
        if (maxlen > 4) {                                // wave-uniform branch
            half8 v0 = *(const half8*)(const void*)((4 < len) ? Hin + (size_t)bc[4] * HROW + sl * 8 : zr);
            half8 v1 = *(const half8*)(const void*)((5 < len) ? Hin + (size_t)bc[5] * HROW + sl * 8 : zr);
            half8 v2 = *(const half8*)(const void*)((6 < len) ? Hin + (size_t)bc[6] * HROW + sl * 8 : zr);
            half8 v3 = *(const half8*)(const void*)((7 < len) ? Hin + (size_t)bc[7] * HROW + sl * 8 : zr);
            half8 s = (v0 + v1) + (v2 + v3);
#pragma unroll
            for (int j = 0; j < 4; ++j) {
                ac[j].x += (float)s[2 * j];
                ac[j].y += (float)s[2 * j + 1];
            }
            if (maxlen > 8) {                            // rare (~4%): shfl loop
                for (int e = 8; e < maxlen; e += 4) {
                    half8 v[4];
#pragma unroll
                    for (int u = 0; u < 4; ++u) {
                        int s_ = __shfl(sidx[p], e + u, 32);
                        v[u] = *(const half8*)(const void*)(
                            ((e + u) < len) ? Hin + (size_t)s_ * HROW + sl * 8 : zr);
                    }
                    half8 s2 = (v[0] + v[1]) + (v[2] + v[3]);
#pragma unroll
                    for (int j = 0; j < 4; ++j) {
                        ac[j].x += (float)s2[2 * j];
                        ac[j].y += (float)s2[2 * j + 1];
                    }
                }
            }
        }

        float iv = 1.0f / fmaxf((float)cn_h, 1.0f);
        __half2 o[4];
#pragma unroll
        for (int j = 0; j < 4; ++j)
            o[j] = __floats2half2_rn(ac[j].x * iv, ac[j].y * iv);
        __half* dst = &TM[nl][hh32 * 256 + sl * 8];      // row stride 1032B: 8B-aligned
        *(uint2*)dst = *(uint2*)&o[0];
        *(uint2*)(dst + 4) = *(uint2*)&o[2];
    }
    __syncthreads();

    // Phase B: MFMA. wave -> branch b = wv>>1, col-half hh = wv&1.
    // TWO A-subtiles (m=0: nodes n0+l15, m=1: nodes n0+16+l15) share each bf.
    int b = wv >> 1;
    int hh = wv & 1;
    int quad = lane >> 4;
    int l15 = lane & 15;

    floatx4 acc[2][4];
#pragma unroll
    for (int t = 0; t < 4; ++t) {
        float bv = bias[l15 * 8 + hh * 4 + t];
#pragma unroll
        for (int m = 0; m < 2; ++m) {
            acc[m][t][0] = bv; acc[m][t][1] = bv; acc[m][t][2] = bv; acc[m][t][3] = bv;
        }
    }

    const __half* hrow0 = Hin + (size_t)(n0 + l15) * HROW + b * Hh + quad * 8;
    const __half* hrow1 = hrow0 + (size_t)16 * HROW;
#pragma unroll
    for (int s = 0; s < 12; ++s) {
        half8 af0, af1;
        if (s < 4) {
            af0 = *(const half8*)(const void*)(hrow0 + s * 32);
            af1 = *(const half8*)(const void*)(hrow1 + s * 32);
        } else {
            int off = ((s >> 2) - 1) * 256 + b * 128 + (s & 3) * 32 + quad * 8;
            af0 = *(const half8*)(const void*)&TM[l15][off];
            af1 = *(const half8*)(const void*)&TM[16 + l15][off];
        }
#pragma unroll
        for (int t = 0; t < 4; ++t) {
            half8 bf = *(const half8*)(const void*)(
                Bsw + ((size_t)((hh * 4 + t) * 12 + s) * 64 + lane) * 8);
            acc[0][t] = __builtin_amdgcn_mfma_f32_16x16x32_f16(af0, bf, acc[0][t], 0, 0, 0);
            acc[1][t] = __builtin_amdgcn_mfma_f32_16x16x32_f16(af1, bf, acc[1][t], 0, 0, 0);
        }
    }

    if (!do_final) {
#pragma unroll
        for (int m = 0; m < 2; ++m) {
#pragma unroll
            for (int r = 0; r < 4; ++r) {
                int node = n0 + m * 16 + quad * 4 + r;
                __half2 o[2];
                o[0] = __floats2half2_rn(acc[m][0][r], acc[m][1][r]);
                o[1] = __floats2half2_rn(acc[m][2][r], acc[m][3][r]);
                *(uint2*)(Hout + (size_t)node * HROW + b * Hh + l15 * 8 + hh * 4) = *(uint2*)o;
            }
        }
    } else {
        __syncthreads();  // all TM reads done before aliased TO writes
#pragma unroll
        for (int m = 0; m < 2; ++m) {
#pragma unroll
            for (int r = 0; r < 4; ++r) {
                int nl = m * 16 + quad * 4 + r;
                __half2 o[2];
                o[0] = __floats2half2_rn(acc[m][0][r], acc[m][1][r]);
                o[1] = __floats2half2_rn(acc[m][2][r], acc[m][3][r]);
                *(uint2*)&TO[nl][b * 128 + l15 * 8 + hh * 4] = *(uint2*)o;
            }
        }
        __syncthreads();
        if (tid < FN * Oo) {
            int node = tid / 3;
            int o3 = tid - node * 3;
            float a = bS[o3], m = bS[o3];
            const __half2* row = (const __half2*)TO[node];
#pragma unroll 4
            for (int k2 = 0; k2 < 64; ++k2) {
                float2 v = __half22float2(row[k2]);
                float2 u = __half22float2(row[64 + k2]);
                float w0 = WoS[(2 * k2) * 3 + o3];
                float w1 = WoS[(2 * k2 + 1) * 3 + o3];
                a += v.x * w0 + v.y * w1;
                m += u.x * w0 + u.y * w1;
            }
            out[(size_t)(n0 + node) * 3 + o3] = a * m;
        }
    }
}

// ================= host =================
extern "C" void kernel_launch(void* const* d_in, const int* in_sizes, int n_in,
                              void* d_out, int out_size, void* d_ws, size_t ws_size,
                              hipStream_t stream) {
    const float* mf = (const float*)d_in[0];
    const float* ff = (const float*)d_in[1];
    const float* W1 = (const float*)d_in[2];
    const float* b1 = (const float*)d_in[3];
    const float* rg1_w = (const float*)d_in[4];
    const float* rg1_root = (const float*)d_in[5];
    const float* rg1_b = (const float*)d_in[6];
    const float* rg2_w = (const float*)d_in[7];
    const float* rg2_root = (const float*)d_in[8];
    const float* rg2_b = (const float*)d_in[9];
    const float* Wo = (const float*)d_in[10];
    const float* bo = (const float*)d_in[11];
    const int* ei = (const int*)d_in[12];
    const int* et = (const int*)d_in[13];
    float* out = (float*)d_out;

    const size_t szBsw = (size_t)8 * 12 * 64 * 8 * 2;  // 96 KB

    // layout for a given bucket capacity; cnt region carries a 512B zero-row tail
    auto layoutNeed = [&](int cap, size_t* offs) {
        size_t o = 0;
        auto take = [&](size_t bytes) { size_t r = o; o += (bytes + 15) & ~(size_t)15; return r; };
        offs[0] = take((size_t)Mm * 4 + 512);        // cnt + zero-row
        offs[1] = take((size_t)Mm * cap * 4);        // eidx (fixed-capacity buckets)
        offs[2] = take(szBsw);                       // Bsw1
        offs[3] = take(szBsw);                       // Bsw2
        offs[4] = take((size_t)Nn * HROW * 2);       // H0
        offs[5] = take((size_t)Nn * HROW * 2);       // H1
        return o;
    };

    size_t offs[6];
    int cap = 64;                                    // ~154.7 MB (proven ws >= ~159.6 MB)
    size_t NEED = layoutNeed(cap, offs);
    if (ws_size < NEED) {
        cap = 32;                                    // ~129.1 MB fallback
        NEED = layoutNeed(cap, offs);
        if (ws_size < NEED) {
            k_diag<<<1, 1, 0, stream>>>(out, (float)ws_size);
            return;
        }
    }

    int* cnt = (int*)((char*)d_ws + offs[0]);
    int* eidx = (int*)((char*)d_ws + offs[1]);
    __half* Bsw1 = (__half*)((char*)d_ws + offs[2]);
    __half* Bsw2 = (__half*)((char*)d_ws + offs[3]);
    __half* H0 = (__half*)((char*)d_ws + offs[4]);
    __half* H1 = (__half*)((char*)d_ws + offs[5]);
    const __half* zrow = (const __half*)((char*)d_ws + offs[0] + (size_t)Mm * 4);

    // 5-dispatch pipeline (prep split for counter attribution)
    hipMemsetAsync(cnt, 0, (size_t)Mm * 4 + 512, stream);
    k_place<<<CNTB4 + SWB, 256, 0, stream>>>(ei, et, cnt, eidx, cap,
                                             rg1_root, rg1_w, rg2_root, rg2_w,
                                             Bsw1, Bsw2);
    k_input<<<INTB, 256, 0, stream>>>(mf, ff, W1, b1, H0);
    k_conv_f<<<Nn / FN, 256, 0, stream>>>(H0, H1, cnt, eidx, cap, Bsw1, rg1_b, zrow,
                                          0, nullptr, nullptr, nullptr);
    k_conv_f<<<Nn / FN, 256, 0, stream>>>(H1, H0, cnt, eidx, cap, Bsw2, rg2_b, zrow,
                                          1, Wo, bo, out);
}

// Round 5
// 344.524 us; speedup vs baseline: 1.2293x; 1.2293x over previous
//
#include <hip/hip_runtime.h>
#include <hip/hip_fp16.h>

#define Nn 100000
#define Ee 800000
#define Dd 16
#define Hh 128
#define Oo 3
#define Rr 2
#define HROW 256      // H row: [h_b0(128) | h_b1(128)]
#define Mm (Rr * Nn)
#define CNTB ((Ee + 255) / 256)                        // 3125 place blocks
#define SWB 48
#define INTB ((Nn + 127) / 128)                        // 782 input blocks
#define NT_IN 128
#define FN 16         // nodes per fused-conv block
#define MPAD 516      // LDS M-row stride (halves)
#define OPAD 264      // LDS out-row stride for fused projection

typedef _Float16 half8 __attribute__((ext_vector_type(8)));
typedef _Float16 half4 __attribute__((ext_vector_type(4)));
typedef float floatx4 __attribute__((ext_vector_type(4)));

// ---------------- diagnostic ----------------
__global__ void k_diag(float* out, float v) { out[0] = v; }

// ================= fused prep: input | direct-place CSR | swizzle =================
// All three paths independent -> pure blockIdx partition, no barriers, NO LDS.
// Input blocks first; place-path atomic latency backfills under their VALU work
// (proven: split version costs ~40us vs fused).
__global__ __launch_bounds__(256) void k_prep_all(
    const int* __restrict__ ei, const int* __restrict__ et,
    int* __restrict__ cnt, int* __restrict__ eidx, int cap,
    const float* __restrict__ r1root, const float* __restrict__ r1w,
    const float* __restrict__ r2root, const float* __restrict__ r2w,
    __half* __restrict__ Bsw1, __half* __restrict__ Bsw2,
    const float* __restrict__ mf, const float* __restrict__ ff,
    const float* __restrict__ W1, const float* __restrict__ b1,
    __half* __restrict__ H) {
    int tid = threadIdx.x;
    int bx = blockIdx.x;

    if (bx < INTB) {
        // ---- input layer: 128-node tile, LDS-free ----
        // w[k][j] loop-invariant per thread -> 16 VGPRs (coalesced loads).
        // x rows are wave-uniform -> scalar loads (readfirstlane forces proof).
        int n0 = bx * NT_IN;
        int j = tid & 127;
        int hf = __builtin_amdgcn_readfirstlane(tid >> 7);
        float wk[Dd];
#pragma unroll
        for (int k = 0; k < Dd; ++k) wk[k] = W1[k * Hh + j];
        float bj = b1[j];
        int nbeg = n0 + hf * 64;
        int nend = nbeg + 64;
        if (nend > Nn) nend = Nn;
#pragma unroll 2
        for (int n = nbeg; n < nend; ++n) {
            const float* xr = mf + (size_t)n * Dd;
            const float* fr = ff + (size_t)n * Dd;
            float a0 = bj, a1 = bj;
#pragma unroll
            for (int k = 0; k < Dd; ++k) {
                float xv = xr[k];
                float fv = fr[k];
                a0 = fmaf(xv, wk[k], a0);          // v_fma: 1 SGPR operand ok
                a1 = fmaf(fv, wk[k], a1);
                a1 = fmaf(-xv, wk[k], a1);         // (fv-xv)*w without 2-SGPR instr
            }
            a0 = a0 > 0.f ? a0 : 0.01f * a0;
            a1 = a1 > 0.f ? a1 : 0.01f * a1;
            H[(size_t)n * HROW + j] = __float2half(a0);
            H[(size_t)n * HROW + Hh + j] = __float2half(a1);
        }
        return;
    }
    int sb = bx - INTB;
    if (sb < CNTB) {
        // ---- direct placement: one edge per thread ----
        // eidx[bucket*cap + atomicAdd(cnt[bucket])] = src. Degrees Poisson(4),
        // cap=64 -> overflow prob ~0; stores clamped, conv clamps length.
        int e = sb * 256 + tid;
        if (e < Ee) {
            int s = ei[e];
            int d = ei[Ee + e];
            int t = et[e];
            int gb = t * Nn + d;
            int pos = atomicAdd(&cnt[gb], 1);
            if (pos < cap) eidx[(size_t)gb * cap + pos] = s;
        }
        return;
    }
    sb -= CNTB;
    {
        // ---- weight swizzle (verified mapping: tile t holds col (l&15)*8+t) ----
        const float* wroot = (sb < 24) ? r1root : r2root;
        const float* wrel = (sb < 24) ? r1w : r2w;
        __half* Bsw = (sb < 24) ? Bsw1 : Bsw2;
        int idx = (sb % 24) * 256 + tid;
        if (idx >= 8 * 12 * 64) return;
        int l = idx & 63;
        int s = (idx >> 6) % 12;
        int t = (idx >> 6) / 12;
        int n = (l & 15) * 8 + t;
        int k0 = s * 32 + (l >> 4) * 8;
        __half tmp[8];
#pragma unroll
        for (int jj = 0; jj < 8; ++jj) {
            int k = k0 + jj;
            float v = (k < Hh) ? wroot[k * Hh + n] : wrel[(size_t)(k - Hh) * Hh + n];
            tmp[jj] = __float2half(v);
        }
        *(uint4*)(Bsw + (size_t)idx * 8) = *(uint4*)tmp;
    }
}

// ---------------- fused conv: reduction-free gather->LDS + MFMA ----
// Phase A (this rev): PAIRED buckets. VGPR_Count=32 at lb(256,8) proved the
// compiler serializes p-iterations (one bucket's state fills the 64-reg budget).
// lb(256,6) -> 85-reg budget; explicit pair issue puts 8 half8 gathers in
// flight per wave (2x MLP) before either accumulate. Tails (deg>4, wave-uniform
// ~50%) keep the proven serial shfl loop. Phase B verbatim r2.
__global__ __launch_bounds__(256, 6) void k_conv_f(const __half* __restrict__ Hin,
                                                   __half* __restrict__ Hout,
                                                   const int* __restrict__ cnt,
                                                   const int* __restrict__ eidx, int cap,
                                                   const __half* __restrict__ Bsw,
                                                   const float* __restrict__ bias,
                                                   const __half* __restrict__ zrow,
                                                   int do_final,
                                                   const float* __restrict__ Wo,
                                                   const float* __restrict__ bo,
                                                   float* __restrict__ out) {
    __shared__ __align__(16) char smem[FN * MPAD * 2];   // 16512 B; TM, later TO (aliased)
    __shared__ float WoS[Hh * Oo];
    __shared__ float bS[Oo];
    auto TM = (__half(*)[MPAD])smem;
    auto TO = (__half(*)[OPAD])smem;

    int tid = threadIdx.x;
    int n0 = blockIdx.x * FN;
    int wv = tid >> 6;
    int lane = tid & 63;

    if (do_final) {
        for (int i = tid; i < Hh * Oo; i += 256) WoS[i] = Wo[i];
        if (tid < Oo) bS[tid] = bo[tid];
    }

    // ---- Phase A ----
    int hh32 = lane >> 5;      // half-wave id == relation t
    int sl = lane & 31;        // sublane within half-wave
    const __half* zr = zrow + sl * 8;

    // hoisted metadata: 8 cnt loads + 4 edge-list loads, all concurrent
    int cn0[4], cn1[4], sidx[4];
#pragma unroll
    for (int p = 0; p < 4; ++p) {
        int gb0 = n0 + wv * 4 + p;                       // relation-0 bucket
        cn0[p] = cnt[gb0];
        cn1[p] = cnt[gb0 + Nn];
        sidx[p] = eidx[(size_t)(hh32 * Nn + gb0) * cap + sl];
    }

#pragma unroll
    for (int pp = 0; pp < 4; pp += 2) {
        int pA = pp, pB = pp + 1;
        int cnA = hh32 ? cn1[pA] : cn0[pA];
        int cnB = hh32 ? cn1[pB] : cn0[pB];
        int lenA = cnA < 32 ? cnA : 32;
        int lenB = cnB < 32 ? cnB : 32;
        int mA = cn0[pA] > cn1[pA] ? cn0[pA] : cn1[pA];
        int mB = cn0[pB] > cn1[pB] ? cn0[pB] : cn1[pB];
        int maxA = mA < 32 ? mA : 32;
        int maxB = mB < 32 ? mB : 32;

        // round-0 edge ids for BOTH buckets (8 shfl, one lgkm drain)
        int bA0 = __shfl(sidx[pA], 0, 32), bA1 = __shfl(sidx[pA], 1, 32);
        int bA2 = __shfl(sidx[pA], 2, 32), bA3 = __shfl(sidx[pA], 3, 32);
        int bB0 = __shfl(sidx[pB], 0, 32), bB1 = __shfl(sidx[pB], 1, 32);
        int bB2 = __shfl(sidx[pB], 2, 32), bB3 = __shfl(sidx[pB], 3, 32);

        // issue all 8 round-0 gathers back-to-back (2x MLP vs serial p-loop)
        half8 vA0 = *(const half8*)(const void*)((0 < lenA) ? Hin + (size_t)bA0 * HROW + sl * 8 : zr);
        half8 vA1 = *(const half8*)(const void*)((1 < lenA) ? Hin + (size_t)bA1 * HROW + sl * 8 : zr);
        half8 vA2 = *(const half8*)(const void*)((2 < lenA) ? Hin + (size_t)bA2 * HROW + sl * 8 : zr);
        half8 vA3 = *(const half8*)(const void*)((3 < lenA) ? Hin + (size_t)bA3 * HROW + sl * 8 : zr);
        half8 vB0 = *(const half8*)(const void*)((0 < lenB) ? Hin + (size_t)bB0 * HROW + sl * 8 : zr);
        half8 vB1 = *(const half8*)(const void*)((1 < lenB) ? Hin + (size_t)bB1 * HROW + sl * 8 : zr);
        half8 vB2 = *(const half8*)(const void*)((2 < lenB) ? Hin + (size_t)bB2 * HROW + sl * 8 : zr);
        half8 vB3 = *(const half8*)(const void*)((3 < lenB) ? Hin + (size_t)bB3 * HROW + sl * 8 : zr);

        float2 acA[4], acB[4];
#pragma unroll
        for (int j = 0; j < 4; ++j) {
            acA[j].x = 0.f; acA[j].y = 0.f;
            acB[j].x = 0.f; acB[j].y = 0.f;
        }
#pragma unroll
        for (int j = 0; j < 4; ++j) {
            acA[j].x += (float)vA0[2 * j] + (float)vA1[2 * j] + (float)vA2[2 * j] + (float)vA3[2 * j];
            acA[j].y += (float)vA0[2 * j + 1] + (float)vA1[2 * j + 1] + (float)vA2[2 * j + 1] + (float)vA3[2 * j + 1];
            acB[j].x += (float)vB0[2 * j] + (float)vB1[2 * j] + (float)vB2[2 * j] + (float)vB3[2 * j];
            acB[j].y += (float)vB0[2 * j + 1] + (float)vB1[2 * j + 1] + (float)vB2[2 * j + 1] + (float)vB3[2 * j + 1];
        }

        // tails (wave-uniform branches; r2-proven serial shfl loop)
        if (maxA > 4) {
            for (int e = 4; e < maxA; e += 4) {
                half8 v[4];
#pragma unroll
                for (int u = 0; u < 4; ++u) {
                    int s_ = __shfl(sidx[pA], e + u, 32);
                    v[u] = *(const half8*)(const void*)(
                        ((e + u) < lenA) ? Hin + (size_t)s_ * HROW + sl * 8 : zr);
                }
#pragma unroll
                for (int u = 0; u < 4; ++u) {
#pragma unroll
                    for (int j = 0; j < 4; ++j) {
                        acA[j].x += (float)v[u][2 * j];
                        acA[j].y += (float)v[u][2 * j + 1];
                    }
                }
            }
        }
        if (maxB > 4) {
            for (int e = 4; e < maxB; e += 4) {
                half8 v[4];
#pragma unroll
                for (int u = 0; u < 4; ++u) {
                    int s_ = __shfl(sidx[pB], e + u, 32);
                    v[u] = *(const half8*)(const void*)(
                        ((e + u) < lenB) ? Hin + (size_t)s_ * HROW + sl * 8 : zr);
                }
#pragma unroll
                for (int u = 0; u < 4; ++u) {
#pragma unroll
                    for (int j = 0; j < 4; ++j) {
                        acB[j].x += (float)v[u][2 * j];
                        acB[j].y += (float)v[u][2 * j + 1];
                    }
                }
            }
        }

        float ivA = 1.0f / fmaxf((float)cnA, 1.0f);
        float ivB = 1.0f / fmaxf((float)cnB, 1.0f);
        __half2 oA[4], oB[4];
#pragma unroll
        for (int j = 0; j < 4; ++j) {
            oA[j] = __floats2half2_rn(acA[j].x * ivA, acA[j].y * ivA);
            oB[j] = __floats2half2_rn(acB[j].x * ivB, acB[j].y * ivB);
        }
        __half* dA = &TM[wv * 4 + pA][hh32 * 256 + sl * 8];   // row stride 1032B: 8B-aligned
        __half* dB = &TM[wv * 4 + pB][hh32 * 256 + sl * 8];
        *(uint2*)dA = *(uint2*)&oA[0];
        *(uint2*)(dA + 4) = *(uint2*)&oA[2];
        *(uint2*)dB = *(uint2*)&oB[0];
        *(uint2*)(dB + 4) = *(uint2*)&oB[2];
    }
    __syncthreads();

    // Phase B: MFMA. wave -> branch b = wv>>1, col-half hh = wv&1  (verbatim r2)
    int b = wv >> 1;
    int hh = wv & 1;
    int quad = lane >> 4;
    int l15 = lane & 15;

    floatx4 acc[4];
#pragma unroll
    for (int t = 0; t < 4; ++t) {
        float bv = bias[l15 * 8 + hh * 4 + t];
        acc[t][0] = bv; acc[t][1] = bv; acc[t][2] = bv; acc[t][3] = bv;
    }

    const __half* hrow = Hin + (size_t)(n0 + l15) * HROW + b * Hh + quad * 8;
#pragma unroll
    for (int s = 0; s < 12; ++s) {
        half8 af;
        if (s < 4)
            af = *(const half8*)(const void*)(hrow + s * 32);
        else
            af = *(const half8*)(const void*)&TM[l15][((s >> 2) - 1) * 256 + b * 128 +
                                                     (s & 3) * 32 + quad * 8];
#pragma unroll
        for (int t = 0; t < 4; ++t) {
            half8 bf = *(const half8*)(const void*)(
                Bsw + ((size_t)((hh * 4 + t) * 12 + s) * 64 + lane) * 8);
            acc[t] = __builtin_amdgcn_mfma_f32_16x16x32_f16(af, bf, acc[t], 0, 0, 0);
        }
    }

    if (!do_final) {
#pragma unroll
        for (int r = 0; r < 4; ++r) {
            int node = n0 + quad * 4 + r;
            __half2 o[2];
            o[0] = __floats2half2_rn(acc[0][r], acc[1][r]);
            o[1] = __floats2half2_rn(acc[2][r], acc[3][r]);
            *(uint2*)(Hout + (size_t)node * HROW + b * Hh + l15 * 8 + hh * 4) = *(uint2*)o;
        }
    } else {
        __syncthreads();  // all TM reads done before aliased TO writes
#pragma unroll
        for (int r = 0; r < 4; ++r) {
            int nl = quad * 4 + r;
            __half2 o[2];
            o[0] = __floats2half2_rn(acc[0][r], acc[1][r]);
            o[1] = __floats2half2_rn(acc[2][r], acc[3][r]);
            *(uint2*)&TO[nl][b * 128 + l15 * 8 + hh * 4] = *(uint2*)o;
        }
        __syncthreads();
        if (tid < FN * Oo) {
            int node = tid / 3;
            int o3 = tid - node * 3;
            float a = bS[o3], m = bS[o3];
            const __half2* row = (const __half2*)TO[node];
#pragma unroll 4
            for (int k2 = 0; k2 < 64; ++k2) {
                float2 v = __half22float2(row[k2]);
                float2 u = __half22float2(row[64 + k2]);
                float w0 = WoS[(2 * k2) * 3 + o3];
                float w1 = WoS[(2 * k2 + 1) * 3 + o3];
                a += v.x * w0 + v.y * w1;
                m += u.x * w0 + u.y * w1;
            }
            out[(size_t)(n0 + node) * 3 + o3] = a * m;
        }
    }
}

// ================= host =================
extern "C" void kernel_launch(void* const* d_in, const int* in_sizes, int n_in,
                              void* d_out, int out_size, void* d_ws, size_t ws_size,
                              hipStream_t stream) {
    const float* mf = (const float*)d_in[0];
    const float* ff = (const float*)d_in[1];
    const float* W1 = (const float*)d_in[2];
    const float* b1 = (const float*)d_in[3];
    const float* rg1_w = (const float*)d_in[4];
    const float* rg1_root = (const float*)d_in[5];
    const float* rg1_b = (const float*)d_in[6];
    const float* rg2_w = (const float*)d_in[7];
    const float* rg2_root = (const float*)d_in[8];
    const float* rg2_b = (const float*)d_in[9];
    const float* Wo = (const float*)d_in[10];
    const float* bo = (const float*)d_in[11];
    const int* ei = (const int*)d_in[12];
    const int* et = (const int*)d_in[13];
    float* out = (float*)d_out;

    const size_t szBsw = (size_t)8 * 12 * 64 * 8 * 2;  // 96 KB

    // layout for a given bucket capacity; cnt region carries a 512B zero-row tail
    auto layoutNeed = [&](int cap, size_t* offs) {
        size_t o = 0;
        auto take = [&](size_t bytes) { size_t r = o; o += (bytes + 15) & ~(size_t)15; return r; };
        offs[0] = take((size_t)Mm * 4 + 512);        // cnt + zero-row
        offs[1] = take((size_t)Mm * cap * 4);        // eidx (fixed-capacity buckets)
        offs[2] = take(szBsw);                       // Bsw1
        offs[3] = take(szBsw);                       // Bsw2
        offs[4] = take((size_t)Nn * HROW * 2);       // H0
        offs[5] = take((size_t)Nn * HROW * 2);       // H1
        return o;
    };

    size_t offs[6];
    int cap = 64;                                    // ~154.7 MB (proven ws >= ~159.6 MB)
    size_t NEED = layoutNeed(cap, offs);
    if (ws_size < NEED) {
        cap = 32;                                    // ~129.1 MB fallback
        NEED = layoutNeed(cap, offs);
        if (ws_size < NEED) {
            k_diag<<<1, 1, 0, stream>>>(out, (float)ws_size);
            return;
        }
    }

    int* cnt = (int*)((char*)d_ws + offs[0]);
    int* eidx = (int*)((char*)d_ws + offs[1]);
    __half* Bsw1 = (__half*)((char*)d_ws + offs[2]);
    __half* Bsw2 = (__half*)((char*)d_ws + offs[3]);
    __half* H0 = (__half*)((char*)d_ws + offs[4]);
    __half* H1 = (__half*)((char*)d_ws + offs[5]);
    const __half* zrow = (const __half*)((char*)d_ws + offs[0] + (size_t)Mm * 4);

    // 4-dispatch pipeline
    hipMemsetAsync(cnt, 0, (size_t)Mm * 4 + 512, stream);
    k_prep_all<<<INTB + CNTB + SWB, 256, 0, stream>>>(ei, et, cnt, eidx, cap,
                                                      rg1_root, rg1_w, rg2_root, rg2_w,
                                                      Bsw1, Bsw2, mf, ff, W1, b1, H0);
    k_conv_f<<<Nn / FN, 256, 0, stream>>>(H0, H1, cnt, eidx, cap, Bsw1, rg1_b, zrow,
                                          0, nullptr, nullptr, nullptr);
    k_conv_f<<<Nn / FN, 256, 0, stream>>>(H1, H0, cnt, eidx, cap, Bsw2, rg2_b, zrow,
                                          1, Wo, bo, out);
}